// Round 10
// baseline (178.430 us; speedup 1.0000x reference)
//
#include <hip/hip_runtime.h>
#include <hip/hip_bf16.h>
#include <math.h>

// Problem constants (fixed by reference setup_inputs)
constexpr int NROWS = 8192;   // B
constexpr int HDIM  = 256;    // H (= K of the GEMM)
constexpr int N2    = 16384;  // 2*B rows of Z
constexpr int TM    = 256;    // tile M = tile N; 16 waves of 64x64 out each
constexpr int BK    = 32;     // K chunk staged per round (8 chunks)
constexpr int NCHUNK = HDIM / BK;     // 8
constexpr int PIECE = TM * BK;        // 8192 elems = 16 KB per piece
constexpr int NTILE = N2 / TM;        // 64 tile-rows
constexpr int NBLK  = NTILE * (NTILE + 1) / 2;  // 2080 upper-tri tiles

// sqrt(2 * log2(e)): Z pre-scaled so Zs_i.Zs_j = 2*log2(e)*cos and
// exp2(acc) == exp(sim/tau), tau = 0.5
constexpr float PRESCALE = 1.69864357f;

typedef __attribute__((ext_vector_type(16))) float floatx16;
typedef __attribute__((ext_vector_type(8))) short shortx8; // 8 bf16 = 4 VGPRs

__device__ __forceinline__ void async_copy16(const void* gptr, void* lptr) {
    __builtin_amdgcn_global_load_lds(
        (const __attribute__((address_space(1))) unsigned int*)gptr,
        (__attribute__((address_space(3))) unsigned int*)lptr, 16, 0, 0);
}

// s_waitcnt immediates (gfx9: vm[3:0], exp[6:4], lgkm[11:8], vm-hi[15:14])
#define WAIT_VM2()   __builtin_amdgcn_s_waitcnt(0x0F72)  // vmcnt(2)
#define WAIT_VM0()   __builtin_amdgcn_s_waitcnt(0x0F70)  // vmcnt(0)
#define MEMFENCE()   __asm__ __volatile__("" ::: "memory")
#define RAW_BARRIER() do { MEMFENCE(); __builtin_amdgcn_s_barrier(); MEMFENCE(); } while (0)

// DPP row_shl add: VALU pipe, not DS (R9: -18us vs ds_bpermute shuffles).
#define DPP_ROW_SHL_ADD(v, CTRL) do {                                        \
    union { float f; int i; } _u, _r; _u.f = (v);                            \
    _r.i = __builtin_amdgcn_update_dpp(0, _u.i, (CTRL), 0xF, 0xF, true);     \
    (v) += _r.f; } while (0)

// ---------------------------------------------------------------------------
// Kernel 1: wave-per-row L2-normalize -> bf16 Z (pre-scaled); pos = cos(x,y).
// Also zeroes rowsum and out (stream-ordered before consumers).
// ---------------------------------------------------------------------------
__global__ __launch_bounds__(256) void normalize_kernel(
    const float* __restrict__ x, const float* __restrict__ y,
    __hip_bfloat16* __restrict__ Z, float* __restrict__ pos,
    float* __restrict__ rowsum, float* __restrict__ out)
{
    const int wave = threadIdx.x >> 6, lane = threadIdx.x & 63;
    const int row  = blockIdx.x * 4 + wave;           // grid 2048 -> 8192 rows

    const float4 xv = ((const float4*)x)[row * 64 + lane];
    const float4 yv = ((const float4*)y)[row * 64 + lane];

    float sx  = xv.x*xv.x + xv.y*xv.y + xv.z*xv.z + xv.w*xv.w;
    float sy  = yv.x*yv.x + yv.y*yv.y + yv.z*yv.z + yv.w*yv.w;
    float sxy = xv.x*yv.x + xv.y*yv.y + xv.z*yv.z + xv.w*yv.w;
    #pragma unroll
    for (int m = 1; m < 64; m <<= 1) {
        sx  += __shfl_xor(sx,  m);
        sy  += __shfl_xor(sy,  m);
        sxy += __shfl_xor(sxy, m);
    }
    const float rxn = rsqrtf(sx), ryn = rsqrtf(sy);
    const float rx = rxn * PRESCALE, ry = ryn * PRESCALE;

    union { ushort4 u; __hip_bfloat16 h[4]; } zx, zy;
    zx.h[0] = __float2bfloat16(xv.x * rx); zx.h[1] = __float2bfloat16(xv.y * rx);
    zx.h[2] = __float2bfloat16(xv.z * rx); zx.h[3] = __float2bfloat16(xv.w * rx);
    zy.h[0] = __float2bfloat16(yv.x * ry); zy.h[1] = __float2bfloat16(yv.y * ry);
    zy.h[2] = __float2bfloat16(yv.z * ry); zy.h[3] = __float2bfloat16(yv.w * ry);
    ((ushort4*)Z)[row * 64 + lane]             = zx.u;
    ((ushort4*)Z)[(row + NROWS) * 64 + lane]   = zy.u;

    if (lane == 0) {
        const float p = sxy * rxn * ryn;
        pos[row]         = p;
        pos[row + NROWS] = p;
    }
    const int gt = blockIdx.x * 256 + threadIdx.x;
    if (gt < N2) rowsum[gt] = 0.f;
    if (gt == 0) out[0] = 0.f;
}

// ---------------------------------------------------------------------------
// Kernel 2: upper-triangle tiled Z·Z^T, fused exp2 + row/col sums.
// R18: R16 chassis (bf16, 16 waves x 64x64 out, BK=32, 3 buffers, proven
// 1-barrier schedule, staging verbatim) with ONLY the MFMA shape changed:
// 16x16x32 -> 32x32x16 (the one axis untouched across R10-R17's invariant
// 24-30% plateau). 32x32x16 bf16 is the fastest measured pipe (2495 vs
// 2075 TF), needs 4x fewer MFMA instructions and acc[2][2] f32x16 = 64
// AGPR (same budget as R16 -> launch_bounds(1024,4) keeps 4 waves/SIMD).
// A/B fragment risk cancels structurally: A and B frags are read with
// IDENTICAL per-lane formulas from identical-format row-major tiles, so
// any intra-lane k-permutation is dot-invariant. C/D layout is the
// HW-verified mapping (m74/m101): col=lane&31,
// row=(q&3)+8*(q>>2)+4*(lane>>5), q in [0,16).
// Frag reads: row r=(band+l31), kstep ks: src 16B-slot c=ks*2+(lane>>5),
// LDS slot = c ^ ((r>>1)&3) (storage XOR carried verbatim). ~4-way bank
// aliasing on the 32-row b128 read (same residual class m201 accepts).
//   body s: if s+1<8 {STAGE(s+1); vmcnt(2)} else vmcnt(0); BARRIER;
//           8x ds_read_b128; 8x MFMA 32x32x16 (2 ksteps x 2x2).
// WAR/RAW: verbatim R16 (3 buffers, stage-before-barrier; all waves past
// barrier(s-1) have body-(s-2) ds_reads retired via lgkm gates + in-order
// DS retirement). No device-scope fences (R5).
// ---------------------------------------------------------------------------
__global__ __launch_bounds__(1024, 4) void simgemm_kernel(
    const __hip_bfloat16* __restrict__ Z, float* __restrict__ rowsum)
{
    // ---- XCD-local block -> (bi,bj) mapping (bijection onto upper tri) ----
    const int b = blockIdx.x;
    const int k = b & 7;        // XCD under round-robin dispatch heuristic
    const int m = b >> 3;       // 0..259 local rank within XCD
    int bi, bj;
    if (m < 36) {
        int ti = (int)((17.0f - sqrtf(289.0f - 8.0f * (float)m)) * 0.5f);
        if (m < ti * (17 - ti) / 2) ti--;
        else if (m >= (ti + 1) * (16 - ti) / 2) ti++;
        const int tj = ti + (m - ti * (17 - ti) / 2);
        bi = k * 8 + ti;
        bj = k * 8 + tj;
    } else {
        const int m2 = m - 36;           // 0..223
        const int hh = m2 >> 5;          // 0..6
        const int r  = m2 & 31;          // 0..31
        const int h  = hh * 8 + k;       // 0..55
        const int q  = h >> 1;           // 0..27
        const int sub = h & 1;
        int gi = 0;
        #pragma unroll
        for (int t = 6; t > 0; --t)
            if (q >= t * (15 - t) / 2) { gi = t; break; }
        const int gj = gi + 1 + (q - gi * (15 - gi) / 2);
        bi = gi * 8 + sub * 4 + (r >> 3);
        bj = gj * 8 + (r & 7);
    }
    const bool diag = (bi == bj);

    // LDS: 3 buffers x (tA 16KB + tB 16KB) = 96KB, + rs/cs 2KB = 98KB
    __shared__ alignas(16) __hip_bfloat16 tiles[6 * PIECE];  // 96 KB
    __shared__ float rs[TM];
    __shared__ float cs[TM];
    __hip_bfloat16* tA = tiles;                  // + buf * 2*PIECE
    __hip_bfloat16* tB = tiles + PIECE;          // + buf * 2*PIECE

    const int tid  = threadIdx.x;
    const int wave = tid >> 6;            // 0..15
    const int lane = tid & 63;
    const int wm   = wave & 3;            // wave row band: rows wm*64..+64
    const int wn   = wave >> 2;           // wave col band: cols wn*64..+64
    const int l31  = lane & 31;
    const int hi   = lane >> 5;           // k-half within a kstep

    if (tid < TM) { rs[tid] = 0.f; cs[tid] = 0.f; }

    // ---- staging addresses (verbatim R16) ----
    const int st_r0  = wave * 16 + (lane >> 2);
    const int st_c   = (lane & 3) ^ ((lane >> 3) & 3);     // source chunk
    const __hip_bfloat16* gA0 = Z + (size_t)(bi * TM + st_r0) * HDIM + st_c * 8;
    const __hip_bfloat16* gB0 = Z + (size_t)(bj * TM + st_r0) * HDIM + st_c * 8;
    __hip_bfloat16* lA0 = tA + (wave * 16) * BK;
    __hip_bfloat16* lB0 = tB + (wave * 16) * BK;

    // ---- fragment read offsets (32x32x16: rows band+l31, k-half hi) ----
    const int xr  = (l31 >> 1) & 3;            // storage slot XOR for row
    const int so0 = ((0 + hi) ^ xr) * 8;       // kstep 0 slot (bf16 elems)
    const int so1 = ((2 + hi) ^ xr) * 8;       // kstep 1 slot
    const int rowA0 = (wm * 64 +  0 + l31) * BK;
    const int rowA1 = (wm * 64 + 32 + l31) * BK;
    const int rowB0 = (wn * 64 +  0 + l31) * BK;
    const int rowB1 = (wn * 64 + 32 + l31) * BK;

    floatx16 acc[2][2] = {};

    // chunk ck -> buffer ck%3
    #define STAGE(ck)  do {                                                  \
        const int _o = ((ck) % 3) * 2 * PIECE;                               \
        async_copy16(gA0 + (ck) * BK, lA0 + _o);                             \
        async_copy16(gB0 + (ck) * BK, lB0 + _o);                             \
    } while (0)

    STAGE(0);   // prologue (2 loads in flight entering body 0)

    #pragma unroll
    for (int s = 0; s < NCHUNK; ++s) {
        if (s + 1 < NCHUNK) { STAGE(s + 1); WAIT_VM2(); }
        else                { WAIT_VM0(); }
        RAW_BARRIER();   // all waves' chunk-s loads landed in buf s%3

        const int bo = (s % 3) * 2 * PIECE;
        shortx8 a0k0 = *(const shortx8*)(tA + bo + rowA0 + so0);
        shortx8 a1k0 = *(const shortx8*)(tA + bo + rowA1 + so0);
        shortx8 b0k0 = *(const shortx8*)(tB + bo + rowB0 + so0);
        shortx8 b1k0 = *(const shortx8*)(tB + bo + rowB1 + so0);
        shortx8 a0k1 = *(const shortx8*)(tA + bo + rowA0 + so1);
        shortx8 a1k1 = *(const shortx8*)(tA + bo + rowA1 + so1);
        shortx8 b0k1 = *(const shortx8*)(tB + bo + rowB0 + so1);
        shortx8 b1k1 = *(const shortx8*)(tB + bo + rowB1 + so1);

        __builtin_amdgcn_s_setprio(1);
        acc[0][0] = __builtin_amdgcn_mfma_f32_32x32x16_bf16(a0k0, b0k0, acc[0][0], 0, 0, 0);
        acc[0][1] = __builtin_amdgcn_mfma_f32_32x32x16_bf16(a0k0, b1k0, acc[0][1], 0, 0, 0);
        acc[1][0] = __builtin_amdgcn_mfma_f32_32x32x16_bf16(a1k0, b0k0, acc[1][0], 0, 0, 0);
        acc[1][1] = __builtin_amdgcn_mfma_f32_32x32x16_bf16(a1k0, b1k0, acc[1][1], 0, 0, 0);
        acc[0][0] = __builtin_amdgcn_mfma_f32_32x32x16_bf16(a0k1, b0k1, acc[0][0], 0, 0, 0);
        acc[0][1] = __builtin_amdgcn_mfma_f32_32x32x16_bf16(a0k1, b1k1, acc[0][1], 0, 0, 0);
        acc[1][0] = __builtin_amdgcn_mfma_f32_32x32x16_bf16(a1k1, b0k1, acc[1][0], 0, 0, 0);
        acc[1][1] = __builtin_amdgcn_mfma_f32_32x32x16_bf16(a1k1, b1k1, acc[1][1], 0, 0, 0);
        __builtin_amdgcn_s_setprio(0);
        // no 2nd barrier / lgkm drain: WAR argument in header comment
    }
    #undef STAGE

    // ---- epilogue: e = exp2(acc) (== exp(sim/tau)), reduce rows & cols ----
    // C/D map (verified m74/m101): col = band + l31,
    //                              row = band + (q&3)+8*(q>>2)+4*hi
    float rp[2][16];           // [fm][q] partial row sums (per-lane: 1 col)
    float cp[2] = {0.f, 0.f};  // [fn] col sums (lane-local across fm,q)
    #pragma unroll
    for (int fm = 0; fm < 2; ++fm)
        #pragma unroll
        for (int q = 0; q < 16; ++q) rp[fm][q] = 0.f;

    if (!diag) {
        #pragma unroll
        for (int fm = 0; fm < 2; ++fm)
            #pragma unroll
            for (int fn = 0; fn < 2; ++fn) {
                const floatx16 a = acc[fm][fn];
                #pragma unroll
                for (int q = 0; q < 16; ++q) {
                    const float e = __builtin_amdgcn_exp2f(a[q]);
                    rp[fm][q] += e;
                    cp[fn]    += e;
                }
            }
    } else {
        #pragma unroll
        for (int fm = 0; fm < 2; ++fm)
            #pragma unroll
            for (int fn = 0; fn < 2; ++fn) {
                const floatx16 a = acc[fm][fn];
                const int cl = wn * 64 + fn * 32 + l31;
                #pragma unroll
                for (int q = 0; q < 16; ++q) {
                    const int rl = wm * 64 + fm * 32 + (q & 3) + 8 * (q >> 2) + 4 * hi;
                    float e = __builtin_amdgcn_exp2f(a[q]);
                    if (cl <= rl) e = 0.f;   // strictly-upper only
                    rp[fm][q] += e;
                    cp[fn]    += e;
                }
            }
    }

    // row sums: reduce over 32 cols = 32 lanes (16-lane DPP + cross-16 shfl)
    #pragma unroll
    for (int fm = 0; fm < 2; ++fm)
        #pragma unroll
        for (int q = 0; q < 16; ++q) {
            float v = rp[fm][q];
            DPP_ROW_SHL_ADD(v, 0x101);   // row_shl:1
            DPP_ROW_SHL_ADD(v, 0x102);   // row_shl:2
            DPP_ROW_SHL_ADD(v, 0x104);   // row_shl:4
            DPP_ROW_SHL_ADD(v, 0x108);   // row_shl:8
            v += __shfl_xor(v, 16);      // combine the two 16-lane halves
            rp[fm][q] = v;               // valid in lanes 0 and 32
        }
    if (l31 == 0) {                      // lanes 0 (hi=0) and 32 (hi=1)
        #pragma unroll
        for (int fm = 0; fm < 2; ++fm)
            #pragma unroll
            for (int q = 0; q < 16; ++q)
                atomicAdd(&rs[wm * 64 + fm * 32 + (q & 3) + 8 * (q >> 2) + 4 * hi],
                          rp[fm][q]);
    }

    // col sums: lane-local over 16 q (+fm folded) -> combine halves
    #pragma unroll
    for (int fn = 0; fn < 2; ++fn)
        cp[fn] += __shfl_xor(cp[fn], 32);
    if (hi == 0) {
        #pragma unroll
        for (int fn = 0; fn < 2; ++fn)
            atomicAdd(&cs[wn * 64 + fn * 32 + l31], cp[fn]);
    }

    __syncthreads();
    if (tid < TM) {
        atomicAdd(&rowsum[(size_t)bi * TM + tid], rs[tid]);
        atomicAdd(&rowsum[(size_t)bj * TM + tid], cs[tid]);
    }
}

// ---------------------------------------------------------------------------
// Kernel 3: loss = mean( log(rowsum_i) - 2*pos_i ), 16 blocks + atomic.
// ---------------------------------------------------------------------------
__global__ __launch_bounds__(1024) void finalize_kernel(
    const float* __restrict__ rowsum, const float* __restrict__ pos,
    float* __restrict__ out)
{
    const int i = threadIdx.x + blockIdx.x * 1024;
    float s = logf(rowsum[i]) - 2.0f * pos[i];
    #pragma unroll
    for (int off = 32; off; off >>= 1) s += __shfl_down(s, off);
    __shared__ float sh[16];
    const int lt = threadIdx.x;
    if ((lt & 63) == 0) sh[lt >> 6] = s;
    __syncthreads();
    if (lt == 0) {
        float tot = 0.f;
        #pragma unroll
        for (int w = 0; w < 16; ++w) tot += sh[w];
        atomicAdd(out, tot / (float)N2);
    }
}

// ---------------------------------------------------------------------------
extern "C" void kernel_launch(void* const* d_in, const int* in_sizes, int n_in,
                              void* d_out, int out_size, void* d_ws, size_t ws_size,
                              hipStream_t stream)
{
    const float* x = (const float*)d_in[0];
    const float* y = (const float*)d_in[1];

    // workspace: Z bf16 [16384*256] (8 MB) | rowsum f32 [16384] | pos f32 [16384]
    __hip_bfloat16* Z = (__hip_bfloat16*)d_ws;
    float* rowsum = (float*)((char*)d_ws + (size_t)N2 * HDIM * sizeof(__hip_bfloat16));
    float* pos    = rowsum + N2;

    normalize_kernel<<<NROWS / 4, 256, 0, stream>>>(x, y, Z, pos, rowsum, (float*)d_out);
    simgemm_kernel<<<NBLK, 1024, 0, stream>>>(Z, rowsum);
    finalize_kernel<<<N2 / 1024, 1024, 0, stream>>>(rowsum, pos, (float*)d_out);
}